// Round 14
// baseline (3107.184 us; speedup 1.0000x reference)
//
#include <hip/hip_runtime.h>
#include <math.h>

typedef unsigned short u16;
typedef unsigned int   u32;
typedef unsigned char  u8;
typedef __attribute__((ext_vector_type(4))) float f32x4;
typedef __attribute__((ext_vector_type(4))) u32   u32x4;
typedef __attribute__((ext_vector_type(8))) int   i32x8;
typedef __attribute__((ext_vector_type(4))) int   i32x4;

#define IMG_W 96
#define IMG_H 96
#define HWSZ  9216
#define CCH   128
#define BATCH 8
#define NT    4

#define PADW  102
#define PADA  (102*102)
#define XQ_BYTES ((size_t)BATCH*PADA*128)      // fp8 state

#define XS_ELEMS (BATCH*CCH*HWSZ)
#define ES_OFF   (4*XS_ELEMS)

__device__ inline u16 f2bf(float f) {
    u32 u = __float_as_uint(f);
    u += 0x7fffu + ((u >> 16) & 1u);
    return (u16)(u >> 16);
}
__device__ inline float bf2f(u16 h) { return __uint_as_float(((u32)h) << 16); }

#define GLD_LDS16(g, l) \
    __builtin_amdgcn_global_load_lds((const __attribute__((address_space(1))) void*)(g), \
                                     (__attribute__((address_space(3))) void*)(l), 16, 0, 0)

// ---------------------------------------------------------------------------
// GroupNorm stats
// ---------------------------------------------------------------------------
__global__ __launch_bounds__(256) void gn_stats_kernel(
    const float* __restrict__ c, float* __restrict__ stats)
{
    const int bg  = blockIdx.x;
    const int tid = threadIdx.x;
    const float4* p4 = (const float4*)(c + (size_t)bg * 18432);
    float s1 = 0.f, s2 = 0.f;
    for (int i = tid; i < 18432/4; i += 256) {
        float4 v = p4[i];
        s1 += v.x + v.y + v.z + v.w;
        s2 += v.x*v.x + v.y*v.y + v.z*v.z + v.w*v.w;
    }
    __shared__ float r1[256], r2[256];
    r1[tid] = s1; r2[tid] = s2;
    __syncthreads();
    for (int s = 128; s > 0; s >>= 1) {
        if (tid < s) { r1[tid] += r1[tid+s]; r2[tid] += r2[tid+s]; }
        __syncthreads();
    }
    if (tid == 0) {
        float mu  = r1[0] * (1.f/18432.f);
        float var = fmaxf(r2[0] * (1.f/18432.f) - mu*mu, 0.f);
        stats[bg*2]   = mu;
        stats[bg*2+1] = rsqrtf(var + 1e-5f);
    }
}

// ---------------------------------------------------------------------------
// Weight prep: conv_w f32 [oc][ic][7][7] -> wq fp8 e4m3 [tap][oc][ic]
// ---------------------------------------------------------------------------
__global__ __launch_bounds__(256) void wprep_kernel(
    const float* __restrict__ cw, u32* __restrict__ wq)
{
    int idx = blockIdx.x * 256 + threadIdx.x;      // < 49*128*32 = 200704
    if (idx >= 200704) return;
    int ic4 = idx & 31;
    int rem = idx >> 5;
    int oc  = rem & 127;
    int tap = rem >> 7;
    const float* s = cw + ((size_t)oc*128 + ic4*4)*49 + tap;
    float v0 = s[0], v1 = s[49], v2 = s[98], v3 = s[147];
    u32 lo = __builtin_amdgcn_cvt_pk_fp8_f32(v0, v1, 0, false);
    u32 pk = __builtin_amdgcn_cvt_pk_fp8_f32(v2, v3, lo, true);
    wq[(size_t)tap*4096 + oc*32 + ic4] = pk;
}

// ---------------------------------------------------------------------------
// cgn prep: GN-affine(c) + conv bias, packed bf16 pairs, planar per group.
// ---------------------------------------------------------------------------
__global__ __launch_bounds__(256) void cprep_kernel(
    const float* __restrict__ c, const float* __restrict__ stats,
    const float* __restrict__ gnw, const float* __restrict__ gnb,
    const float* __restrict__ cb, u32* __restrict__ cgn)
{
    const int bg  = blockIdx.y;            // b*64+g
    const int pix = blockIdx.x * 1024 + threadIdx.x * 4;
    const int b   = bg >> 6, g = bg & 63;
    const int ch0 = 2*g, ch1 = 2*g + 1;
    const float mu = stats[bg*2], rs = stats[bg*2+1];
    const float w0 = gnw[ch0]*rs, b0 = gnb[ch0] - mu*w0 + cb[ch0];
    const float w1 = gnw[ch1]*rs, b1 = gnb[ch1] - mu*w1 + cb[ch1];
    f32x4 c0 = *(const f32x4*)(c + ((size_t)(b*128+ch0))*HWSZ + pix);
    f32x4 c1 = *(const f32x4*)(c + ((size_t)(b*128+ch1))*HWSZ + pix);
    u32x4 v;
    #pragma unroll
    for (int j = 0; j < 4; ++j)
        v[j] = (u32)f2bf(fmaf(c0[j], w0, b0)) | ((u32)f2bf(fmaf(c1[j], w1, b1)) << 16);
    *(u32x4*)(cgn + (size_t)bg*HWSZ + pix) = v;
}

// ---------------------------------------------------------------------------
// x0 prep: LDS transpose, normalize pairs, fp8 channels-last padded state.
// ---------------------------------------------------------------------------
__global__ __launch_bounds__(256) void xprep_kernel(
    const float* __restrict__ x, u8* __restrict__ xq)
{
    __shared__ float s_t[128][65];
    const int b  = blockIdx.y;
    const int p0 = blockIdx.x * 64;
    const int tid = threadIdx.x;
    for (int it = 0; it < 32; ++it) {
        int idx = it*256 + tid;
        int ch = idx >> 6, p = idx & 63;
        s_t[ch][p] = x[((size_t)b*128 + ch)*HWSZ + p0 + p];
    }
    __syncthreads();
    for (int it = 0; it < 16; ++it) {
        int idx = it*256 + tid;          // 64 px * 64 pairs
        int g = idx & 63, p = idx >> 6;
        int pix = p0 + p;
        int py = pix / 96, px = pix - py*96;
        float v0 = s_t[2*g][p], v1 = s_t[2*g+1][p];
        float sc = 1.f / fmaxf(sqrtf(v0*v0 + v1*v1), 1e-12f);
        u32 pk = __builtin_amdgcn_cvt_pk_fp8_f32(v0*sc, v1*sc, 0, false);
        *(u16*)(xq + ((size_t)b*PADA + (py+3)*PADW + (px+3))*128 + 2*g) = (u16)(pk & 0xffff);
    }
}

// ---------------------------------------------------------------------------
// Fused implicit-GEMM conv (fp8 MX MFMA, K=128) + Kuramoto + energy.
// 192 thr = 3 waves; tile 144 px (12x12) x 128 oc; WAVE = 48 px x 128 oc.
// OPERAND-SWAPPED: mfma(A=weights, B=pixels) -> D col(l15)=pixel,
// row(l4*4+j)=oc (lane-local oscillator pairs, coalesced epilogue).
// K-loop: 7x7 row-unrolled (inner 7 taps straight-line, compile-time c2);
// per-row state = 6 scalar adds into statically-indexed arrays (no tables,
// no scratch). Per tap (r11 schedule): {READ_FRAGS(t); lgkm0+vmcnt0
// [B(t+1) issued a tap ago -> ~free]; s_barrier; ISSUE_B(t+2); MFMA(t)}.
// Odd blocks sleep ~1.5k cy once to anti-phase the 2 blocks/CU.
// ---------------------------------------------------------------------------
__global__ __launch_bounds__(192, 2) void convk8(
    const u8*    __restrict__ xq_in,
    const u8*    __restrict__ wq,
    const u32*   __restrict__ cgn,
    const float* __restrict__ omega,
    float* __restrict__ xout, u8* __restrict__ xq_out,
    float* __restrict__ es, int write_q)
{
    __shared__ __align__(16) u8 s_a[324*128];     // 41472 B
    __shared__ __align__(16) u8 s_bb[2][16384];
    __shared__ float s_red[192];

    const int tid = threadIdx.x;
    const int w   = tid >> 6, l = tid & 63;       // w = wm (0..2)
    const int b   = blockIdx.y;
    const int bx  = blockIdx.x;          // 0..63
    const int tpy = bx >> 3, tpx = bx & 7;
    const int l15 = l & 15, l4 = l >> 4;

    const u8* abase = xq_in + ((size_t)b*PADA + (size_t)tpy*12*PADW + (size_t)tpx*12)*128;

    // ---- stage A halo: 324 px x 8 granules, 2D-uniform source pre-swizzle ----
    #pragma unroll 1
    for (int it = 0; it < 14; ++it) {
        int i = it*192 + tid;
        if (i < 2592) {
            int p = i >> 3, g = i & 7;
            int hr = p / 18, hc = p - hr*18;
            int sxy = (4*hr + hc) & 7;
            const u8* src = abase + ((size_t)hr*PADW + hc)*128 + ((g ^ sxy) << 4);
            GLD_LDS16(src, s_a + i*16);
        }
    }

    // wave-uniform B staging: 6 GLDS per thread (wrap duplicates benign).
#define ISSUE_B(wsrcp, dstbuf)                                             \
    { const u8* wsrc_ = (wsrcp);                                           \
      _Pragma("unroll")                                                    \
      for (int it_ = 0; it_ < 6; ++it_) {                                  \
          int i_ = (it_*192 + tid) & 1023;                                 \
          int oc_ = i_ >> 3, g_ = i_ & 7;                                  \
          GLD_LDS16(wsrc_ + oc_*128 + ((g_ ^ (oc_ & 7)) << 4),             \
                    (dstbuf) + i_*16);                                     \
      } }

    ISSUE_B(wq,         s_bb[0]);
    ISSUE_B(wq + 16384, s_bb[1]);
    __syncthreads();                     // full drain once: A, B(0), B(1) resident

    // per-lane fragment bases (pixel byte base + swizzle phase)
    const int kloA = (l4*2) << 4;
    int pbR[3], sbzR[3];                 // advanced per row (statically indexed)
    #pragma unroll
    for (int mi = 0; mi < 3; ++mi) {
        int m = w*48 + mi*16 + l15;
        int pr = m/12, pc = m - pr*12;
        pbR[mi]  = (pr*18 + pc) * 128;
        sbzR[mi] = (4*pr + pc) & 7;
    }
    int boff[8];
    #pragma unroll
    for (int ni = 0; ni < 8; ++ni) {
        int oc = ni*16 + l15;
        boff[ni] = oc*128 + (((l4*2) ^ (oc & 7)) << 4);
    }

    f32x4 acc[3][8] = {};
    i32x8 af[3], bfr[8];

    if (bx & 1) __builtin_amdgcn_s_sleep(24);   // anti-phase the 2 blocks/CU

    const u8* wnext = wq + 2*16384;      // B source for tap t+2 (uniform)

    #pragma unroll 1
    for (int r = 0; r < 7; ++r) {
        u8* bufR  = s_bb[r & 1];         // buffer parity for even c2
        u8* bufRx = s_bb[(r & 1) ^ 1];   // parity for odd c2
        #pragma unroll
        for (int c2 = 0; c2 < 7; ++c2) {
            u8* sbuf = (c2 & 1) ? bufRx : bufR;
            const int pdc = c2 * 128;    // compile-time byte offset within row

            // ---- READ_FRAGS(t) ----
            #pragma unroll
            for (int mi = 0; mi < 3; ++mi) {
                int sx = ((sbzR[mi] + c2) & 7) << 4;
                int a0 = kloA ^ sx;
                const u8* base = s_a + pbR[mi] + pdc;
                i32x4 lo = *(const i32x4*)(base + a0);
                i32x4 hi = *(const i32x4*)(base + (a0 ^ 16));
                af[mi] = __builtin_shufflevector(lo, hi, 0,1,2,3,4,5,6,7);
            }
            #pragma unroll
            for (int ni = 0; ni < 8; ++ni) {
                i32x4 lo = *(const i32x4*)(sbuf + boff[ni]);
                i32x4 hi = *(const i32x4*)(sbuf + (boff[ni] ^ 16));
                bfr[ni] = __builtin_shufflevector(lo, hi, 0,1,2,3,4,5,6,7);
            }
            // own frag reads serviced + own B(t+1) (issued last tap) landed
            asm volatile("s_waitcnt lgkmcnt(0) vmcnt(0)" ::: "memory");
            __builtin_amdgcn_s_barrier();            // buffer handoff point
            if ((r < 6) || (c2 < 5)) {               // t+2 <= 48
                ISSUE_B(wnext, sbuf);                // overwrite freed buffer
                wnext += 16384;
            }
            // ---- MFMA(t): operand-swapped (weights first) ----
            __builtin_amdgcn_s_setprio(1);
            #pragma unroll
            for (int mi = 0; mi < 3; ++mi)
                #pragma unroll
                for (int ni = 0; ni < 8; ++ni)
                    acc[mi][ni] = __builtin_amdgcn_mfma_scale_f32_16x16x128_f8f6f4(
                        bfr[ni], af[mi], acc[mi][ni], 0, 0, 0, 0x7F, 0, 0x7F);
            __builtin_amdgcn_s_setprio(0);
        }
        #pragma unroll
        for (int mi = 0; mi < 3; ++mi) {
            pbR[mi]  += 18*128;          // next halo row
            sbzR[mi] += 4;               // swizzle phase += 4 (masked at use)
        }
    }

    // ---- epilogue: Kuramoto update (lane-local pairs, coalesced I/O) ----
    const float om = omega[0];
    const size_t nb = (size_t)b * (CCH*HWSZ);
    float esum = 0.f;

    #pragma unroll
    for (int mi = 0; mi < 3; ++mi) {
        const int m   = w*48 + mi*16 + l15;       // pixel index in tile
        const int pr  = m/12, pc = m - pr*12;
        const int py  = tpy*12 + pr;
        const int px  = tpx*12 + pc;
        const int pixel = py*96 + px;
        const int hp  = (pr+3)*18 + (pc+3);       // halo pixel
        const int hs  = (4*(pr+3) + (pc+3)) & 7;  // its swizzle
        const u8* albase = s_a + hp*128;
        #pragma unroll
        for (int ni = 0; ni < 8; ++ni) {
            const int ocb = ni*16 + l4*4;         // 4 oc, this lane
            float res[4];
            #pragma unroll
            for (int p2 = 0; p2 < 2; ++p2) {
                const int oc0 = ocb + p2*2;
                const int g   = oc0 >> 1;
                // x pair from LDS A-halo (swizzled)
                int goff = (((oc0 >> 4) ^ hs) << 4) + (oc0 & 15);
                int xv   = (int)*(const u16*)(albase + goff);
                float x0 = __builtin_amdgcn_cvt_f32_fp8(xv, 0);
                float x1 = __builtin_amdgcn_cvt_f32_fp8(xv, 1);
                // GN'd c (bf16 pair), coalesced across lanes
                u32 cg = cgn[(size_t)(b*64 + g)*HWSZ + pixel];
                float y0 = acc[mi][ni][p2*2]   + bf2f((u16)(cg & 0xffff));
                float y1 = acc[mi][ni][p2*2+1] + bf2f((u16)(cg >> 16));
                float inner = x0*y0 + x1*y1;
                esum += inner;
                float xn0 = x0 - om*x1 + (y0 - inner*x0);
                float xn1 = x1 + om*x0 + (y1 - inner*x1);
                float sc2 = 1.f / fmaxf(sqrtf(xn0*xn0 + xn1*xn1), 1e-12f);
                res[p2*2]   = xn0 * sc2;
                res[p2*2+1] = xn1 * sc2;
            }
            if (write_q) {
                u32 pk0 = __builtin_amdgcn_cvt_pk_fp8_f32(res[0], res[1], 0, false);
                u32 pk1 = __builtin_amdgcn_cvt_pk_fp8_f32(res[2], res[3], 0, false);
                u32 word = (pk0 & 0xffffu) | (pk1 << 16);
                *(u32*)(xq_out + ((size_t)b*PADA + (size_t)(py+3)*PADW + (px+3))*128 + ocb)
                    = word;
            }
            #pragma unroll
            for (int j = 0; j < 4; ++j)
                xout[nb + (size_t)(ocb + j)*HWSZ + pixel] = res[j];
        }
    }

    // ---- energy: block reduce, one atomic per block ----
    s_red[tid] = esum;
    __syncthreads();
    if (tid < 64) s_red[tid] += s_red[tid+64] + s_red[tid+128];
    __syncthreads();
    for (int s = 32; s > 0; s >>= 1) {
        if (tid < s) s_red[tid] += s_red[tid+s];
        __syncthreads();
    }
    if (tid == 0) atomicAdd(es + b, -s_red[0]);
#undef ISSUE_B
}

// ---------------------------------------------------------------------------
// Fallback (fp32 VALU path) if ws too small.
// ---------------------------------------------------------------------------
template<bool FIRST>
__global__ __launch_bounds__(256) void conv_kur_kernel(
    const float* __restrict__ xin, const float* __restrict__ craw,
    const float* __restrict__ cw, const float* __restrict__ cb,
    const float* __restrict__ gnw, const float* __restrict__ gnb,
    const float* __restrict__ omega, const float* __restrict__ stats,
    float* __restrict__ xout, float* __restrict__ es)
{
    __shared__ float s_in[2][22][24];
    __shared__ float s_w[2][49][16];
    __shared__ float s_red[256];
    const int tid = threadIdx.x;
    const int tile = blockIdx.x, ocb = blockIdx.y, b = blockIdx.z;
    const int row0 = (tile / 6) * 16, col0 = (tile % 6) * 16;
    const int pxg = tid & 63, ocg = tid >> 6;
    const int ry = pxg >> 2, sx = pxg & 3;
    const size_t in_base = (size_t)b * CCH * HWSZ;
    float acc[4][4] = {};
    for (int icp = 0; icp < 64; ++icp) {
        __syncthreads();
        for (int idx = tid; idx < 968; idx += 256) {
            int ch = idx / 484, rem = idx - ch*484;
            int r = rem / 22, cl = rem - r*22;
            int gr = row0 + r - 3, gc = col0 + cl - 3;
            float v = 0.f;
            if (gr >= 0 && gr < IMG_H && gc >= 0 && gc < IMG_W)
                v = xin[in_base + (size_t)(icp*2 + ch)*HWSZ + gr*IMG_W + gc];
            s_in[ch][r][cl] = v;
        }
        {
            int combo = tid & 31, q = tid >> 5;
            if (q < 7) {
                int ch = combo >> 4, j = combo & 15;
                const float* wp = cw + ((size_t)(ocb*16 + j)*CCH + icp*2 + ch)*49 + q*7;
                #pragma unroll
                for (int t7 = 0; t7 < 7; ++t7) s_w[ch][q*7 + t7][j] = wp[t7];
            }
        }
        __syncthreads();
        if (FIRST) {
            for (int idx = tid; idx < 484; idx += 256) {
                int r = idx / 22, cl = idx - r*22;
                float v0 = s_in[0][r][cl], v1 = s_in[1][r][cl];
                float sc = 1.f / fmaxf(sqrtf(v0*v0 + v1*v1), 1e-12f);
                s_in[0][r][cl] = v0*sc; s_in[1][r][cl] = v1*sc;
            }
            __syncthreads();
        }
        #pragma unroll
        for (int ch = 0; ch < 2; ++ch)
            #pragma unroll
            for (int dy = 0; dy < 7; ++dy) {
                float r[12];
                const float* rp = &s_in[ch][ry + dy][sx*4];
                #pragma unroll
                for (int i = 0; i < 12; ++i) r[i] = rp[i];
                #pragma unroll
                for (int dx = 0; dx < 7; ++dx) {
                    const float* wv = &s_w[ch][dy*7 + dx][ocg*4];
                    float w0 = wv[0], w1 = wv[1], w2 = wv[2], w3 = wv[3];
                    #pragma unroll
                    for (int p = 0; p < 4; ++p) {
                        float iv = r[dx + p];
                        acc[0][p] = fmaf(w0, iv, acc[0][p]);
                        acc[1][p] = fmaf(w1, iv, acc[1][p]);
                        acc[2][p] = fmaf(w2, iv, acc[2][p]);
                        acc[3][p] = fmaf(w3, iv, acc[3][p]);
                    }
                }
            }
    }
    const int py = row0 + ry, px0 = col0 + sx*4;
    const float om = omega[0];
    const int ocbase = ocb*16 + ocg*4;
    float esum = 0.f;
    #pragma unroll
    for (int pr = 0; pr < 2; ++pr) {
        const int oc0 = ocbase + pr*2;
        const int g = oc0 >> 1;
        const float mu = stats[(b*64+g)*2], rs = stats[(b*64+g)*2+1];
        const float w0s = gnw[oc0]*rs,   b0s = gnb[oc0]   - mu*rs*gnw[oc0];
        const float w1s = gnw[oc0+1]*rs, b1s = gnb[oc0+1] - mu*rs*gnw[oc0+1];
        const float cb0 = cb[oc0], cb1 = cb[oc0+1];
        const size_t off = in_base + (size_t)oc0*HWSZ + py*IMG_W + px0;
        const float* c0p = craw + off; const float* c1p = c0p + HWSZ;
        const float* x0p = xin  + off; const float* x1p = x0p + HWSZ;
        float* o0p = xout + off; float* o1p = o0p + HWSZ;
        #pragma unroll
        for (int p = 0; p < 4; ++p) {
            float x0 = x0p[p], x1 = x1p[p];
            if (FIRST) {
                float sc = 1.f / fmaxf(sqrtf(x0*x0 + x1*x1), 1e-12f);
                x0 *= sc; x1 *= sc;
            }
            float y0 = acc[pr*2][p]   + cb0 + fmaf(c0p[p], w0s, b0s);
            float y1 = acc[pr*2+1][p] + cb1 + fmaf(c1p[p], w1s, b1s);
            float inner = x0*y0 + x1*y1;
            esum += inner;
            float xn0 = x0 - om*x1 + (y0 - inner*x0);
            float xn1 = x1 + om*x0 + (y1 - inner*x1);
            float sc2 = 1.f / fmaxf(sqrtf(xn0*xn0 + xn1*xn1), 1e-12f);
            o0p[p] = xn0*sc2; o1p[p] = xn1*sc2;
        }
    }
    s_red[tid] = esum;
    __syncthreads();
    for (int s = 128; s > 0; s >>= 1) {
        if (tid < s) s_red[tid] += s_red[tid + s];
        __syncthreads();
    }
    if (tid == 0) atomicAdd(es + b, -s_red[0]);
}

// ---------------------------------------------------------------------------
extern "C" void kernel_launch(void* const* d_in, const int* in_sizes, int n_in,
                              void* d_out, int out_size, void* d_ws, size_t ws_size,
                              hipStream_t stream)
{
    const float* x   = (const float*)d_in[0];
    const float* c   = (const float*)d_in[1];
    const float* cw  = (const float*)d_in[2];
    const float* cb  = (const float*)d_in[3];
    const float* gnw = (const float*)d_in[4];
    const float* gnb = (const float*)d_in[5];
    const float* om  = (const float*)d_in[6];
    float* out = (float*)d_out;

    float* stats = (float*)d_ws;
    hipMemsetAsync(out + ES_OFF, 0, 40 * sizeof(float), stream);
    gn_stats_kernel<<<512, 256, 0, stream>>>(c, stats);

    const size_t OFF_WQ  = 4096;
    const size_t OFF_CGN = OFF_WQ  + 802816;     //   806,912
    const size_t OFF_XQA = OFF_CGN + 18874368;   // 19,681,280
    const size_t OFF_XQB = OFF_XQA + XQ_BYTES;   // 30,334,976
    const size_t WS_NEED = OFF_XQB + XQ_BYTES;   // 40,988,672

    if (ws_size >= WS_NEED) {
        u32* wq   = (u32*)((char*)d_ws + OFF_WQ);
        u32* cgnp = (u32*)((char*)d_ws + OFF_CGN);
        u8*  xqA  = (u8*) ((char*)d_ws + OFF_XQA);
        u8*  xqB  = (u8*) ((char*)d_ws + OFF_XQB);

        hipMemsetAsync(xqA, 0, XQ_BYTES, stream);
        hipMemsetAsync(xqB, 0, XQ_BYTES, stream);
        wprep_kernel<<<(200704 + 255)/256, 256, 0, stream>>>(cw, wq);
        cprep_kernel<<<dim3(9, 512), 256, 0, stream>>>(c, stats, gnw, gnb, cb, cgnp);
        xprep_kernel<<<dim3(144, 8), 256, 0, stream>>>(x, xqA);

        dim3 grid(64, 8);
        u8* xin  = xqA;
        u8* xalt = xqB;
        for (int t = 0; t < NT; ++t) {
            float* xo  = out + (size_t)t * XS_ELEMS;
            float* esl = out + ES_OFF + (t + 1) * 8;
            int wb = (t < NT-1) ? 1 : 0;
            convk8<<<grid, 192, 0, stream>>>((const u8*)xin, (const u8*)wq, cgnp,
                                             om, xo, xalt, esl, wb);
            u8* tmp = xin; xin = xalt; xalt = tmp;
        }
    } else {
        dim3 grid(36, 8, 8);
        const float* xin = x;
        for (int t = 0; t < NT; ++t) {
            float* xo  = out + (size_t)t * XS_ELEMS;
            float* esl = out + ES_OFF + (t + 1) * 8;
            if (t == 0)
                conv_kur_kernel<true ><<<grid, 256, 0, stream>>>(xin, c, cw, cb, gnw, gnb, om, stats, xo, esl);
            else
                conv_kur_kernel<false><<<grid, 256, 0, stream>>>(xin, c, cw, cb, gnw, gnb, om, stats, xo, esl);
            xin = xo;
        }
    }
}

// Round 15
// 362.497 us; speedup vs baseline: 8.5716x; 8.5716x over previous
//
#include <hip/hip_runtime.h>
#include <math.h>

typedef unsigned short u16;
typedef unsigned int   u32;
typedef unsigned char  u8;
typedef __attribute__((ext_vector_type(4))) float f32x4;
typedef __attribute__((ext_vector_type(4))) u32   u32x4;
typedef __attribute__((ext_vector_type(8))) int   i32x8;
typedef __attribute__((ext_vector_type(4))) int   i32x4;

#define IMG_W 96
#define IMG_H 96
#define HWSZ  9216
#define CCH   128
#define BATCH 8
#define NT    4

#define PADW  102
#define PADA  (102*102)
#define XQ_BYTES ((size_t)BATCH*PADA*128)      // fp8 state

#define XS_ELEMS (BATCH*CCH*HWSZ)
#define ES_OFF   (4*XS_ELEMS)

__device__ inline u16 f2bf(float f) {
    u32 u = __float_as_uint(f);
    u += 0x7fffu + ((u >> 16) & 1u);
    return (u16)(u >> 16);
}
__device__ inline float bf2f(u16 h) { return __uint_as_float(((u32)h) << 16); }

#define GLD_LDS16(g, l) \
    __builtin_amdgcn_global_load_lds((const __attribute__((address_space(1))) void*)(g), \
                                     (__attribute__((address_space(3))) void*)(l), 16, 0, 0)

// ---------------------------------------------------------------------------
// GroupNorm stats
// ---------------------------------------------------------------------------
__global__ __launch_bounds__(256) void gn_stats_kernel(
    const float* __restrict__ c, float* __restrict__ stats)
{
    const int bg  = blockIdx.x;
    const int tid = threadIdx.x;
    const float4* p4 = (const float4*)(c + (size_t)bg * 18432);
    float s1 = 0.f, s2 = 0.f;
    for (int i = tid; i < 18432/4; i += 256) {
        float4 v = p4[i];
        s1 += v.x + v.y + v.z + v.w;
        s2 += v.x*v.x + v.y*v.y + v.z*v.z + v.w*v.w;
    }
    __shared__ float r1[256], r2[256];
    r1[tid] = s1; r2[tid] = s2;
    __syncthreads();
    for (int s = 128; s > 0; s >>= 1) {
        if (tid < s) { r1[tid] += r1[tid+s]; r2[tid] += r2[tid+s]; }
        __syncthreads();
    }
    if (tid == 0) {
        float mu  = r1[0] * (1.f/18432.f);
        float var = fmaxf(r2[0] * (1.f/18432.f) - mu*mu, 0.f);
        stats[bg*2]   = mu;
        stats[bg*2+1] = rsqrtf(var + 1e-5f);
    }
}

// ---------------------------------------------------------------------------
// Weight prep: conv_w f32 [oc][ic][7][7] -> wq fp8 e4m3 [tap][oc][ic]
// ---------------------------------------------------------------------------
__global__ __launch_bounds__(256) void wprep_kernel(
    const float* __restrict__ cw, u32* __restrict__ wq)
{
    int idx = blockIdx.x * 256 + threadIdx.x;      // < 49*128*32 = 200704
    if (idx >= 200704) return;
    int ic4 = idx & 31;
    int rem = idx >> 5;
    int oc  = rem & 127;
    int tap = rem >> 7;
    const float* s = cw + ((size_t)oc*128 + ic4*4)*49 + tap;
    float v0 = s[0], v1 = s[49], v2 = s[98], v3 = s[147];
    u32 lo = __builtin_amdgcn_cvt_pk_fp8_f32(v0, v1, 0, false);
    u32 pk = __builtin_amdgcn_cvt_pk_fp8_f32(v2, v3, lo, true);
    wq[(size_t)tap*4096 + oc*32 + ic4] = pk;
}

// ---------------------------------------------------------------------------
// cgn prep: GN-affine(c) + conv bias, packed bf16 pairs, planar per group.
// ---------------------------------------------------------------------------
__global__ __launch_bounds__(256) void cprep_kernel(
    const float* __restrict__ c, const float* __restrict__ stats,
    const float* __restrict__ gnw, const float* __restrict__ gnb,
    const float* __restrict__ cb, u32* __restrict__ cgn)
{
    const int bg  = blockIdx.y;            // b*64+g
    const int pix = blockIdx.x * 1024 + threadIdx.x * 4;
    const int b   = bg >> 6, g = bg & 63;
    const int ch0 = 2*g, ch1 = 2*g + 1;
    const float mu = stats[bg*2], rs = stats[bg*2+1];
    const float w0 = gnw[ch0]*rs, b0 = gnb[ch0] - mu*w0 + cb[ch0];
    const float w1 = gnw[ch1]*rs, b1 = gnb[ch1] - mu*w1 + cb[ch1];
    f32x4 c0 = *(const f32x4*)(c + ((size_t)(b*128+ch0))*HWSZ + pix);
    f32x4 c1 = *(const f32x4*)(c + ((size_t)(b*128+ch1))*HWSZ + pix);
    u32x4 v;
    #pragma unroll
    for (int j = 0; j < 4; ++j)
        v[j] = (u32)f2bf(fmaf(c0[j], w0, b0)) | ((u32)f2bf(fmaf(c1[j], w1, b1)) << 16);
    *(u32x4*)(cgn + (size_t)bg*HWSZ + pix) = v;
}

// ---------------------------------------------------------------------------
// x0 prep: LDS transpose, normalize pairs, fp8 channels-last padded state.
// ---------------------------------------------------------------------------
__global__ __launch_bounds__(256) void xprep_kernel(
    const float* __restrict__ x, u8* __restrict__ xq)
{
    __shared__ float s_t[128][65];
    const int b  = blockIdx.y;
    const int p0 = blockIdx.x * 64;
    const int tid = threadIdx.x;
    for (int it = 0; it < 32; ++it) {
        int idx = it*256 + tid;
        int ch = idx >> 6, p = idx & 63;
        s_t[ch][p] = x[((size_t)b*128 + ch)*HWSZ + p0 + p];
    }
    __syncthreads();
    for (int it = 0; it < 16; ++it) {
        int idx = it*256 + tid;          // 64 px * 64 pairs
        int g = idx & 63, p = idx >> 6;
        int pix = p0 + p;
        int py = pix / 96, px = pix - py*96;
        float v0 = s_t[2*g][p], v1 = s_t[2*g+1][p];
        float sc = 1.f / fmaxf(sqrtf(v0*v0 + v1*v1), 1e-12f);
        u32 pk = __builtin_amdgcn_cvt_pk_fp8_f32(v0*sc, v1*sc, 0, false);
        *(u16*)(xq + ((size_t)b*PADA + (py+3)*PADW + (px+3))*128 + 2*g) = (u16)(pk & 0xffff);
    }
}

// ---------------------------------------------------------------------------
// Fused implicit-GEMM conv (fp8 MX MFMA, K=128) + Kuramoto + energy.
// 192 thr = 3 waves; tile 144 px (12x12) x 128 oc; WAVE = 48 px x 128 oc
// (arithmetic intensity 69.8 FLOP/LDS-byte).
// OPERAND-SWAPPED: mfma(A=weights, B=pixels) -> D col(l15)=pixel,
// row(l4*4+j)=oc (lane-local oscillator pairs, coalesced epilogue).
// K-loop (r12-verified DYNAMIC loop — unrolling spills, r13/r14):
// per tap {READ_FRAGS(t); lgkm0+vmcnt0 [B(t+1) issued a tap ago -> ~free];
// s_barrier; ISSUE_B(t+2); MFMA(t)}. Odd blocks sleep once (~1.5k cy) to
// anti-phase the 2 blocks/CU (LDS bursts overlap the other block's MFMAs).
// ---------------------------------------------------------------------------
__global__ __launch_bounds__(192, 2) void convk8(
    const u8*    __restrict__ xq_in,
    const u8*    __restrict__ wq,
    const u32*   __restrict__ cgn,
    const float* __restrict__ omega,
    float* __restrict__ xout, u8* __restrict__ xq_out,
    float* __restrict__ es, int write_q)
{
    __shared__ __align__(16) u8 s_a[324*128];     // 41472 B
    __shared__ __align__(16) u8 s_bb[2][16384];
    __shared__ float s_red[192];

    const int tid = threadIdx.x;
    const int w   = tid >> 6, l = tid & 63;       // w = wm (0..2)
    const int b   = blockIdx.y;
    const int bx  = blockIdx.x;          // 0..63
    const int tpy = bx >> 3, tpx = bx & 7;
    const int l15 = l & 15, l4 = l >> 4;

    const u8* abase = xq_in + ((size_t)b*PADA + (size_t)tpy*12*PADW + (size_t)tpx*12)*128;

    // ---- stage A halo: 324 px x 8 granules, 2D-uniform source pre-swizzle ----
    #pragma unroll 1
    for (int it = 0; it < 14; ++it) {
        int i = it*192 + tid;
        if (i < 2592) {
            int p = i >> 3, g = i & 7;
            int hr = p / 18, hc = p - hr*18;
            int sxy = (4*hr + hc) & 7;
            const u8* src = abase + ((size_t)hr*PADW + hc)*128 + ((g ^ sxy) << 4);
            GLD_LDS16(src, s_a + i*16);
        }
    }

    // wave-uniform B staging: 6 GLDS per thread (wrap duplicates benign).
#define ISSUE_B(ksrc, dstbuf)                                              \
    { const u8* wsrc_ = wq + (size_t)(ksrc)*16384;                         \
      _Pragma("unroll")                                                    \
      for (int it_ = 0; it_ < 6; ++it_) {                                  \
          int i_ = (it_*192 + tid) & 1023;                                 \
          int oc_ = i_ >> 3, g_ = i_ & 7;                                  \
          GLD_LDS16(wsrc_ + oc_*128 + ((g_ ^ (oc_ & 7)) << 4),             \
                    (dstbuf) + i_*16);                                     \
      } }

    ISSUE_B(0, s_bb[0]);
    ISSUE_B(1, s_bb[1]);
    __syncthreads();                     // full drain once: A, B(0), B(1) resident

    // per-lane fragment bases (pixel linear + swizzle base)
    int pb[3], sbz[3];
    #pragma unroll
    for (int mi = 0; mi < 3; ++mi) {
        int m = w*48 + mi*16 + l15;
        int pr = m/12, pc = m - pr*12;
        pb[mi]  = pr*18 + pc;
        sbz[mi] = (4*pr + pc) & 7;
    }
    int boff[8];
    #pragma unroll
    for (int ni = 0; ni < 8; ++ni) {
        int oc = ni*16 + l15;
        boff[ni] = oc*128 + (((l4*2) ^ (oc & 7)) << 4);
    }
    const int kloA = (l4*2) << 4;

#define READ_FRAGS(AF, BF, sbuf)                                           \
    { _Pragma("unroll")                                                    \
      for (int mi_ = 0; mi_ < 3; ++mi_) {                                  \
          int plin_ = pb[mi_] + pdN;                                       \
          int sx_   = ((sbz[mi_] + sdN) & 7) << 4;                         \
          const u8* base_ = s_a + plin_*128;                               \
          int a0_ = kloA ^ sx_;                                            \
          i32x4 lo_ = *(const i32x4*)(base_ + a0_);                        \
          i32x4 hi_ = *(const i32x4*)(base_ + (a0_ ^ 16));                 \
          AF[mi_] = __builtin_shufflevector(lo_, hi_, 0,1,2,3,4,5,6,7);    \
      }                                                                    \
      _Pragma("unroll")                                                    \
      for (int ni_ = 0; ni_ < 8; ++ni_) {                                  \
          i32x4 lo_ = *(const i32x4*)((sbuf) + boff[ni_]);                 \
          i32x4 hi_ = *(const i32x4*)((sbuf) + (boff[ni_] ^ 16));          \
          BF[ni_] = __builtin_shufflevector(lo_, hi_, 0,1,2,3,4,5,6,7);    \
      } }

// OPERAND SWAP: first MFMA arg = weights frag, second = pixels frag.
#define DO_MFMA(AF, BF)                                                    \
    __builtin_amdgcn_s_setprio(1);                                         \
    _Pragma("unroll")                                                      \
    for (int mi_ = 0; mi_ < 3; ++mi_)                                      \
        _Pragma("unroll")                                                  \
        for (int ni_ = 0; ni_ < 8; ++ni_)                                  \
            acc[mi_][ni_] = __builtin_amdgcn_mfma_scale_f32_16x16x128_f8f6f4( \
                BF[ni_], AF[mi_], acc[mi_][ni_], 0, 0, 0, 0x7F, 0, 0x7F);  \
    __builtin_amdgcn_s_setprio(0);

#define ADV { if (++txc == 7) { txc = 0; pdN += 12; sdN = (sdN + 6) & 7; } \
              else            { ++pdN;  sdN = (sdN + 1) & 7; } }

    f32x4 acc[3][8] = {};
    i32x8 af[3], bfr[8];
    int pdN = 0, sdN = 0, txc = 0;

    if (bx & 1) __builtin_amdgcn_s_sleep(24);   // anti-phase the 2 blocks/CU

    #pragma unroll 1
    for (int t = 0; t < 49; ++t) {
        READ_FRAGS(af, bfr, s_bb[t & 1]);          // tap t
        ADV;
        // own frag reads serviced + own B(t+1) (issued last tap) landed
        asm volatile("s_waitcnt lgkmcnt(0) vmcnt(0)" ::: "memory");
        __builtin_amdgcn_s_barrier();              // buffer handoff point
        if (t + 2 < 49) ISSUE_B(t+2, s_bb[t & 1]); // overwrite freed buffer
        DO_MFMA(af, bfr);                          // overlaps next tap's reads
    }

    // ---- epilogue: Kuramoto update (lane-local pairs, coalesced I/O) ----
    const float om = omega[0];
    const size_t nb = (size_t)b * (CCH*HWSZ);
    float esum = 0.f;

    #pragma unroll
    for (int mi = 0; mi < 3; ++mi) {
        const int m   = w*48 + mi*16 + l15;       // pixel index in tile
        const int pr  = m/12, pc = m - pr*12;
        const int py  = tpy*12 + pr;
        const int px  = tpx*12 + pc;
        const int pixel = py*96 + px;
        const int hp  = (pr+3)*18 + (pc+3);       // halo pixel
        const int hs  = (4*(pr+3) + (pc+3)) & 7;  // its swizzle
        const u8* albase = s_a + hp*128;
        #pragma unroll
        for (int ni = 0; ni < 8; ++ni) {
            const int ocb = ni*16 + l4*4;         // 4 oc, this lane
            float res[4];
            #pragma unroll
            for (int p2 = 0; p2 < 2; ++p2) {
                const int oc0 = ocb + p2*2;
                const int g   = oc0 >> 1;
                // x pair from LDS A-halo (swizzled)
                int goff = (((oc0 >> 4) ^ hs) << 4) + (oc0 & 15);
                int xv   = (int)*(const u16*)(albase + goff);
                float x0 = __builtin_amdgcn_cvt_f32_fp8(xv, 0);
                float x1 = __builtin_amdgcn_cvt_f32_fp8(xv, 1);
                // GN'd c (bf16 pair), coalesced across lanes
                u32 cg = cgn[(size_t)(b*64 + g)*HWSZ + pixel];
                float y0 = acc[mi][ni][p2*2]   + bf2f((u16)(cg & 0xffff));
                float y1 = acc[mi][ni][p2*2+1] + bf2f((u16)(cg >> 16));
                float inner = x0*y0 + x1*y1;
                esum += inner;
                float xn0 = x0 - om*x1 + (y0 - inner*x0);
                float xn1 = x1 + om*x0 + (y1 - inner*x1);
                float sc2 = 1.f / fmaxf(sqrtf(xn0*xn0 + xn1*xn1), 1e-12f);
                res[p2*2]   = xn0 * sc2;
                res[p2*2+1] = xn1 * sc2;
            }
            if (write_q) {
                u32 pk0 = __builtin_amdgcn_cvt_pk_fp8_f32(res[0], res[1], 0, false);
                u32 pk1 = __builtin_amdgcn_cvt_pk_fp8_f32(res[2], res[3], 0, false);
                u32 word = (pk0 & 0xffffu) | (pk1 << 16);
                *(u32*)(xq_out + ((size_t)b*PADA + (size_t)(py+3)*PADW + (px+3))*128 + ocb)
                    = word;
            }
            #pragma unroll
            for (int j = 0; j < 4; ++j)
                xout[nb + (size_t)(ocb + j)*HWSZ + pixel] = res[j];
        }
    }

    // ---- energy: block reduce, one atomic per block ----
    s_red[tid] = esum;
    __syncthreads();
    if (tid < 64) s_red[tid] += s_red[tid+64] + s_red[tid+128];
    __syncthreads();
    for (int s = 32; s > 0; s >>= 1) {
        if (tid < s) s_red[tid] += s_red[tid+s];
        __syncthreads();
    }
    if (tid == 0) atomicAdd(es + b, -s_red[0]);
#undef ISSUE_B
#undef READ_FRAGS
#undef DO_MFMA
#undef ADV
}

// ---------------------------------------------------------------------------
// Fallback (fp32 VALU path) if ws too small.
// ---------------------------------------------------------------------------
template<bool FIRST>
__global__ __launch_bounds__(256) void conv_kur_kernel(
    const float* __restrict__ xin, const float* __restrict__ craw,
    const float* __restrict__ cw, const float* __restrict__ cb,
    const float* __restrict__ gnw, const float* __restrict__ gnb,
    const float* __restrict__ omega, const float* __restrict__ stats,
    float* __restrict__ xout, float* __restrict__ es)
{
    __shared__ float s_in[2][22][24];
    __shared__ float s_w[2][49][16];
    __shared__ float s_red[256];
    const int tid = threadIdx.x;
    const int tile = blockIdx.x, ocb = blockIdx.y, b = blockIdx.z;
    const int row0 = (tile / 6) * 16, col0 = (tile % 6) * 16;
    const int pxg = tid & 63, ocg = tid >> 6;
    const int ry = pxg >> 2, sx = pxg & 3;
    const size_t in_base = (size_t)b * CCH * HWSZ;
    float acc[4][4] = {};
    for (int icp = 0; icp < 64; ++icp) {
        __syncthreads();
        for (int idx = tid; idx < 968; idx += 256) {
            int ch = idx / 484, rem = idx - ch*484;
            int r = rem / 22, cl = rem - r*22;
            int gr = row0 + r - 3, gc = col0 + cl - 3;
            float v = 0.f;
            if (gr >= 0 && gr < IMG_H && gc >= 0 && gc < IMG_W)
                v = xin[in_base + (size_t)(icp*2 + ch)*HWSZ + gr*IMG_W + gc];
            s_in[ch][r][cl] = v;
        }
        {
            int combo = tid & 31, q = tid >> 5;
            if (q < 7) {
                int ch = combo >> 4, j = combo & 15;
                const float* wp = cw + ((size_t)(ocb*16 + j)*CCH + icp*2 + ch)*49 + q*7;
                #pragma unroll
                for (int t7 = 0; t7 < 7; ++t7) s_w[ch][q*7 + t7][j] = wp[t7];
            }
        }
        __syncthreads();
        if (FIRST) {
            for (int idx = tid; idx < 484; idx += 256) {
                int r = idx / 22, cl = idx - r*22;
                float v0 = s_in[0][r][cl], v1 = s_in[1][r][cl];
                float sc = 1.f / fmaxf(sqrtf(v0*v0 + v1*v1), 1e-12f);
                s_in[0][r][cl] = v0*sc; s_in[1][r][cl] = v1*sc;
            }
            __syncthreads();
        }
        #pragma unroll
        for (int ch = 0; ch < 2; ++ch)
            #pragma unroll
            for (int dy = 0; dy < 7; ++dy) {
                float r[12];
                const float* rp = &s_in[ch][ry + dy][sx*4];
                #pragma unroll
                for (int i = 0; i < 12; ++i) r[i] = rp[i];
                #pragma unroll
                for (int dx = 0; dx < 7; ++dx) {
                    const float* wv = &s_w[ch][dy*7 + dx][ocg*4];
                    float w0 = wv[0], w1 = wv[1], w2 = wv[2], w3 = wv[3];
                    #pragma unroll
                    for (int p = 0; p < 4; ++p) {
                        float iv = r[dx + p];
                        acc[0][p] = fmaf(w0, iv, acc[0][p]);
                        acc[1][p] = fmaf(w1, iv, acc[1][p]);
                        acc[2][p] = fmaf(w2, iv, acc[2][p]);
                        acc[3][p] = fmaf(w3, iv, acc[3][p]);
                    }
                }
            }
    }
    const int py = row0 + ry, px0 = col0 + sx*4;
    const float om = omega[0];
    const int ocbase = ocb*16 + ocg*4;
    float esum = 0.f;
    #pragma unroll
    for (int pr = 0; pr < 2; ++pr) {
        const int oc0 = ocbase + pr*2;
        const int g = oc0 >> 1;
        const float mu = stats[(b*64+g)*2], rs = stats[(b*64+g)*2+1];
        const float w0s = gnw[oc0]*rs,   b0s = gnb[oc0]   - mu*rs*gnw[oc0];
        const float w1s = gnw[oc0+1]*rs, b1s = gnb[oc0+1] - mu*rs*gnw[oc0+1];
        const float cb0 = cb[oc0], cb1 = cb[oc0+1];
        const size_t off = in_base + (size_t)oc0*HWSZ + py*IMG_W + px0;
        const float* c0p = craw + off; const float* c1p = c0p + HWSZ;
        const float* x0p = xin  + off; const float* x1p = x0p + HWSZ;
        float* o0p = xout + off; float* o1p = o0p + HWSZ;
        #pragma unroll
        for (int p = 0; p < 4; ++p) {
            float x0 = x0p[p], x1 = x1p[p];
            if (FIRST) {
                float sc = 1.f / fmaxf(sqrtf(x0*x0 + x1*x1), 1e-12f);
                x0 *= sc; x1 *= sc;
            }
            float y0 = acc[pr*2][p]   + cb0 + fmaf(c0p[p], w0s, b0s);
            float y1 = acc[pr*2+1][p] + cb1 + fmaf(c1p[p], w1s, b1s);
            float inner = x0*y0 + x1*y1;
            esum += inner;
            float xn0 = x0 - om*x1 + (y0 - inner*x0);
            float xn1 = x1 + om*x0 + (y1 - inner*x1);
            float sc2 = 1.f / fmaxf(sqrtf(xn0*xn0 + xn1*xn1), 1e-12f);
            o0p[p] = xn0*sc2; o1p[p] = xn1*sc2;
        }
    }
    s_red[tid] = esum;
    __syncthreads();
    for (int s = 128; s > 0; s >>= 1) {
        if (tid < s) s_red[tid] += s_red[tid + s];
        __syncthreads();
    }
    if (tid == 0) atomicAdd(es + b, -s_red[0]);
}

// ---------------------------------------------------------------------------
extern "C" void kernel_launch(void* const* d_in, const int* in_sizes, int n_in,
                              void* d_out, int out_size, void* d_ws, size_t ws_size,
                              hipStream_t stream)
{
    const float* x   = (const float*)d_in[0];
    const float* c   = (const float*)d_in[1];
    const float* cw  = (const float*)d_in[2];
    const float* cb  = (const float*)d_in[3];
    const float* gnw = (const float*)d_in[4];
    const float* gnb = (const float*)d_in[5];
    const float* om  = (const float*)d_in[6];
    float* out = (float*)d_out;

    float* stats = (float*)d_ws;
    hipMemsetAsync(out + ES_OFF, 0, 40 * sizeof(float), stream);
    gn_stats_kernel<<<512, 256, 0, stream>>>(c, stats);

    const size_t OFF_WQ  = 4096;
    const size_t OFF_CGN = OFF_WQ  + 802816;     //   806,912
    const size_t OFF_XQA = OFF_CGN + 18874368;   // 19,681,280
    const size_t OFF_XQB = OFF_XQA + XQ_BYTES;   // 30,334,976
    const size_t WS_NEED = OFF_XQB + XQ_BYTES;   // 40,988,672

    if (ws_size >= WS_NEED) {
        u32* wq   = (u32*)((char*)d_ws + OFF_WQ);
        u32* cgnp = (u32*)((char*)d_ws + OFF_CGN);
        u8*  xqA  = (u8*) ((char*)d_ws + OFF_XQA);
        u8*  xqB  = (u8*) ((char*)d_ws + OFF_XQB);

        hipMemsetAsync(xqA, 0, XQ_BYTES, stream);
        hipMemsetAsync(xqB, 0, XQ_BYTES, stream);
        wprep_kernel<<<(200704 + 255)/256, 256, 0, stream>>>(cw, wq);
        cprep_kernel<<<dim3(9, 512), 256, 0, stream>>>(c, stats, gnw, gnb, cb, cgnp);
        xprep_kernel<<<dim3(144, 8), 256, 0, stream>>>(x, xqA);

        dim3 grid(64, 8);
        u8* xin  = xqA;
        u8* xalt = xqB;
        for (int t = 0; t < NT; ++t) {
            float* xo  = out + (size_t)t * XS_ELEMS;
            float* esl = out + ES_OFF + (t + 1) * 8;
            int wb = (t < NT-1) ? 1 : 0;
            convk8<<<grid, 192, 0, stream>>>((const u8*)xin, (const u8*)wq, cgnp,
                                             om, xo, xalt, esl, wb);
            u8* tmp = xin; xin = xalt; xalt = tmp;
        }
    } else {
        dim3 grid(36, 8, 8);
        const float* xin = x;
        for (int t = 0; t < NT; ++t) {
            float* xo  = out + (size_t)t * XS_ELEMS;
            float* esl = out + ES_OFF + (t + 1) * 8;
            if (t == 0)
                conv_kur_kernel<true ><<<grid, 256, 0, stream>>>(xin, c, cw, cb, gnw, gnb, om, stats, xo, esl);
            else
                conv_kur_kernel<false><<<grid, 256, 0, stream>>>(xin, c, cw, cb, gnw, gnb, om, stats, xo, esl);
            xin = xo;
        }
    }
}